// Round 1
// baseline (469.465 us; speedup 1.0000x reference)
//
#include <hip/hip_runtime.h>
#include <hip/hip_bf16.h>

// RK4 step of Gray-Scott reaction-diffusion, fully fused single kernel.
// Grid: 16 x 2 x 1024 x 1024 f32, periodic boundary (1024 pow2 -> wrap via & 1023).
// 6th-order Laplacian: radius-3 cross stencil; RK4 fused cone radius = 12.

#define TS   32          // output tile
#define RAD  12          // fused halo radius (4 stages x 3)
#define INW  56          // TS + 2*RAD
#define S1   50          // k1/Y1 region (halo 9)
#define S2   44          // k2/Y2 region (halo 6)
#define S3   38          // k3/Y3 region (halo 3)

// Stencil weights, replicate numpy's f32 op order: (w / (dx*dx)) / 180
#define W0 ((-980.0f / 1e-4f) / 180.0f)
#define W1 ((  270.0f / 1e-4f) / 180.0f)
#define W2 (( -27.0f / 1e-4f) / 180.0f)
#define W3 ((   2.0f / 1e-4f) / 180.0f)

#define LAP(Bf, yy, xx) ( W0 * Bf[yy][xx] \
  + W1 * (Bf[(yy)-1][xx] + Bf[(yy)+1][xx] + Bf[yy][(xx)-1] + Bf[yy][(xx)+1]) \
  + W2 * (Bf[(yy)-2][xx] + Bf[(yy)+2][xx] + Bf[yy][(xx)-2] + Bf[yy][(xx)+2]) \
  + W3 * (Bf[(yy)-3][xx] + Bf[(yy)+3][xx] + Bf[yy][(xx)-3] + Bf[yy][(xx)+3]) )

__global__ __launch_bounds__(256, 2) void rcnn_rk4_fused(
    const float* __restrict__ h,
    const float* __restrict__ pCA, const float* __restrict__ pCB,
    const float* __restrict__ pNA, const float* __restrict__ pNB,
    const float* __restrict__ pf,  const float* __restrict__ pk,
    float* __restrict__ out)
{
    __shared__ float Au[INW][INW+1], Av[INW][INW+1];   // u0, v0 (input + halo 12)
    __shared__ float Bu[S1][S1+1],  Bv[S1][S1+1];      // Y1, later reused for Y3
    __shared__ float Cu[S2][S2+1],  Cv[S2][S2+1];      // Y2
    __shared__ float ACu[TS][TS+1], ACv[TS][TS+1];     // k1 + 2k2 + 2k3 accumulator

    const int tid = threadIdx.x;
    const int b   = blockIdx.z;
    const int x0  = blockIdx.x * TS - RAD;
    const int y0  = blockIdx.y * TS - RAD;

    const float CA = pCA[0], CB = pCB[0];
    const float NA = pNA[0], NB = pNB[0];
    const float ff = pf[0],  kk = pk[0];
    const float mu_u = 4e-5f / (1.0f + expf(-CA));
    const float mu_v = 4e-5f / (1.0f + expf(-CB));
    const float kpf  = kk + ff;

    const size_t baseU = ((size_t)b * 2 + 0) * 1024 * 1024;
    const size_t baseV = baseU + 1024 * 1024;

    // ---- load u0, v0 tile with periodic halo ----
    for (int i = tid; i < INW * INW; i += 256) {
        int iy = i / INW, ix = i % INW;
        int gy = (y0 + iy) & 1023;
        int gx = (x0 + ix) & 1023;
        size_t off = (size_t)gy * 1024 + gx;
        Au[iy][ix] = h[baseU + off];
        Av[iy][ix] = h[baseV + off];
    }
    __syncthreads();

    // ---- stage 1: k1 = f(u0,v0) over [3,53)^2 ; Y1 = u0 + dt/2*k1 ----
    for (int i = tid; i < S1 * S1; i += 256) {
        int y = i / S1 + 3, x = i % S1 + 3;
        float u = Au[y][x], v = Av[y][x];
        float uv2 = u * v * v;
        float ku = mu_u * LAP(Au, y, x) + NA * uv2 + ff * (1.0f - u);
        float kv = mu_v * LAP(Av, y, x) + NB * uv2 - kpf * v;
        Bu[y-3][x-3] = u + 0.25f * ku;
        Bv[y-3][x-3] = v + 0.25f * kv;
        if (y >= RAD && y < RAD+TS && x >= RAD && x < RAD+TS) {
            ACu[y-RAD][x-RAD] = ku;   // weight 1 (init)
            ACv[y-RAD][x-RAD] = kv;
        }
    }
    __syncthreads();

    // ---- stage 2: k2 = f(Y1) over [6,50)^2 ; Y2 = u0 + dt/2*k2 ----
    for (int i = tid; i < S2 * S2; i += 256) {
        int y = i / S2 + 6, x = i % S2 + 6;
        int by = y - 3, bx = x - 3;
        float u = Bu[by][bx], v = Bv[by][bx];
        float uv2 = u * v * v;
        float ku = mu_u * LAP(Bu, by, bx) + NA * uv2 + ff * (1.0f - u);
        float kv = mu_v * LAP(Bv, by, bx) + NB * uv2 - kpf * v;
        Cu[y-6][x-6] = Au[y][x] + 0.25f * ku;
        Cv[y-6][x-6] = Av[y][x] + 0.25f * kv;
        if (y >= RAD && y < RAD+TS && x >= RAD && x < RAD+TS) {
            ACu[y-RAD][x-RAD] += 2.0f * ku;
            ACv[y-RAD][x-RAD] += 2.0f * kv;
        }
    }
    __syncthreads();

    // ---- stage 3: k3 = f(Y2) over [9,47)^2 ; Y3 = u0 + dt*k3 (into B) ----
    for (int i = tid; i < S3 * S3; i += 256) {
        int y = i / S3 + 9, x = i % S3 + 9;
        int cy = y - 6, cx = x - 6;
        float u = Cu[cy][cx], v = Cv[cy][cx];
        float uv2 = u * v * v;
        float ku = mu_u * LAP(Cu, cy, cx) + NA * uv2 + ff * (1.0f - u);
        float kv = mu_v * LAP(Cv, cy, cx) + NB * uv2 - kpf * v;
        Bu[y-9][x-9] = Au[y][x] + 0.5f * ku;
        Bv[y-9][x-9] = Av[y][x] + 0.5f * kv;
        if (y >= RAD && y < RAD+TS && x >= RAD && x < RAD+TS) {
            ACu[y-RAD][x-RAD] += 2.0f * ku;
            ACv[y-RAD][x-RAD] += 2.0f * kv;
        }
    }
    __syncthreads();

    // ---- stage 4: k4 = f(Y3) over [12,44)^2 ; write output ----
    for (int i = tid; i < TS * TS; i += 256) {
        int y = i / TS + RAD, x = i % TS + RAD;
        int by = y - 9, bx = x - 9;
        float u = Bu[by][bx], v = Bv[by][bx];
        float uv2 = u * v * v;
        float ku = mu_u * LAP(Bu, by, bx) + NA * uv2 + ff * (1.0f - u);
        float kv = mu_v * LAP(Bv, by, bx) + NB * uv2 - kpf * v;
        float outU = Au[y][x] + (0.5f / 6.0f) * (ACu[y-RAD][x-RAD] + ku);
        float outV = Av[y][x] + (0.5f / 6.0f) * (ACv[y-RAD][x-RAD] + kv);
        int gy = y0 + y;   // in [blockIdx.y*32, +32), no wrap needed
        int gx = x0 + x;
        size_t off = (size_t)gy * 1024 + gx;
        out[baseU + off] = outU;
        out[baseV + off] = outV;
    }
}

extern "C" void kernel_launch(void* const* d_in, const int* in_sizes, int n_in,
                              void* d_out, int out_size, void* d_ws, size_t ws_size,
                              hipStream_t stream) {
    const float* h   = (const float*)d_in[0];
    const float* pCA = (const float*)d_in[1];
    const float* pCB = (const float*)d_in[2];
    const float* pNA = (const float*)d_in[3];
    const float* pNB = (const float*)d_in[4];
    const float* pf  = (const float*)d_in[5];
    const float* pk  = (const float*)d_in[6];
    float* out = (float*)d_out;

    dim3 grid(1024 / TS, 1024 / TS, 16);
    dim3 block(256);
    rcnn_rk4_fused<<<grid, block, 0, stream>>>(h, pCA, pCB, pNA, pNB, pf, pk, out);
}

// Round 2
// 404.839 us; speedup vs baseline: 1.1596x; 1.1596x over previous
//
#include <hip/hip_runtime.h>
#include <hip/hip_bf16.h>

// RK4 Gray-Scott, fused single kernel, float4/ds_read_b128 stencil version.
// Logical tile coords: x,y in [0,56); output = [12,44)^2. Physical LDS col:
//   A: p = x + 4 (left pad for center-window reads), stride 68
//   B, C: p = x, stride 56
//   ACC: p = x - 12, stride 36
// All group starts x0 are multiples of 4 -> every LDS float4 access is
// 16B-aligned. Strides mod 32 != 0 to spread bank quads across rows.

#define TS   32
#define RAD  12

#define ASTR 68
#define BSTR 56
#define CSTR 56
#define WSTR 36

#define W0 ((-980.0f / 1e-4f) / 180.0f)
#define W1 ((  270.0f / 1e-4f) / 180.0f)
#define W2 (( -27.0f / 1e-4f) / 180.0f)
#define W3 ((   2.0f / 1e-4f) / 180.0f)

__device__ __forceinline__ float4 f4_add(float4 a, float4 b) {
    return make_float4(a.x + b.x, a.y + b.y, a.z + b.z, a.w + b.w);
}
__device__ __forceinline__ float4 f4_fma(float s, float4 a, float4 b) {
    return make_float4(fmaf(s, a.x, b.x), fmaf(s, a.y, b.y),
                       fmaf(s, a.z, b.z), fmaf(s, a.w, b.w));
}
__device__ __forceinline__ float4 f4_mul(float s, float4 a) {
    return make_float4(s * a.x, s * a.y, s * a.z, s * a.w);
}
__device__ __forceinline__ float el(const float4& v, int j) { return (&v.x)[j]; }
__device__ __forceinline__ float& elr(float4& v, int j) { return (&v.x)[j]; }

// 13-point Laplacian for 4 consecutive points starting at physical col p0
// (p0 % 4 == 0). ry = row index of the center row in this array's row space.
// Returns lap quad and the center quad (field value at the 4 points).
__device__ __forceinline__ void lap4(const float* __restrict__ base, int ry, int p0,
                                     int stride, float4& lap, float4& ctr)
{
    const float* row = base + ry * stride;
    float4 c0 = *(const float4*)(row + p0 - 4);
    float4 c1 = *(const float4*)(row + p0);
    float4 c2 = *(const float4*)(row + p0 + 4);
    float4 n1 = *(const float4*)(base + (ry - 1) * stride + p0);
    float4 s1 = *(const float4*)(base + (ry + 1) * stride + p0);
    float4 n2 = *(const float4*)(base + (ry - 2) * stride + p0);
    float4 s2 = *(const float4*)(base + (ry + 2) * stride + p0);
    float4 n3 = *(const float4*)(base + (ry - 3) * stride + p0);
    float4 s3 = *(const float4*)(base + (ry + 3) * stride + p0);

    // vertical contribution (vectorizable)
    float4 vp = f4_fma(W1, f4_add(n1, s1),
                f4_fma(W2, f4_add(n2, s2),
                f4_mul(W3, f4_add(n3, s3))));

    float r[12] = { c0.x, c0.y, c0.z, c0.w,
                    c1.x, c1.y, c1.z, c1.w,
                    c2.x, c2.y, c2.z, c2.w };
    #pragma unroll
    for (int j = 0; j < 4; ++j) {
        float hp = fmaf(W1, r[3 + j] + r[5 + j],
                   fmaf(W2, r[2 + j] + r[6 + j],
                        W3 * (r[1 + j] + r[7 + j])));
        elr(lap, j) = fmaf(W0, r[4 + j], hp + el(vp, j));
    }
    ctr = c1;
}

__global__ __launch_bounds__(256, 2) void rcnn_rk4_fused(
    const float* __restrict__ h,
    const float* __restrict__ pCA, const float* __restrict__ pCB,
    const float* __restrict__ pNA, const float* __restrict__ pNB,
    const float* __restrict__ pf,  const float* __restrict__ pk,
    float* __restrict__ out)
{
    __shared__ __align__(16) float Au[56][ASTR], Av[56][ASTR];
    __shared__ __align__(16) float Bu[50][BSTR], Bv[50][BSTR];
    __shared__ __align__(16) float Cu[44][CSTR], Cv[44][CSTR];
    __shared__ __align__(16) float ACu[32][WSTR], ACv[32][WSTR];

    const int tid = threadIdx.x;
    const int b   = blockIdx.z;

    const float CA = pCA[0], CB = pCB[0];
    const float NA = pNA[0], NB = pNB[0];
    const float ff = pf[0],  kk = pk[0];
    const float mu_u = 4e-5f / (1.0f + expf(-CA));
    const float mu_v = 4e-5f / (1.0f + expf(-CB));
    const float kpf  = kk + ff;

    const size_t baseU = ((size_t)b * 2 + 0) * 1024 * 1024;
    const size_t baseV = baseU + 1024 * 1024;

    const int y0 = blockIdx.y * TS - RAD;
    const int xg = blockIdx.x * TS - RAD;

    // ---- load u0,v0 (56x56 logical) as float4, wrap-safe (whole quads wrap) ----
    for (int i = tid; i < 56 * 14; i += 256) {
        int r = i / 14, m = i % 14;
        int gy = (y0 + r) & 1023;
        int gx = (xg + 4 * m) & 1023;      // xg+4m ≡ 0 (mod 4), 1024 % 4 == 0
        const size_t off = (size_t)gy * 1024 + gx;
        *(float4*)&Au[r][4 * m + 4] = *(const float4*)(h + baseU + off);
        *(float4*)&Av[r][4 * m + 4] = *(const float4*)(h + baseV + off);
    }
    __syncthreads();

    // ---- stage 1: k1 over [3,53)^2 ; Y1 = u0 + 0.25 k1 -> B ----
    for (int i = tid; i < 50 * 14; i += 256) {
        int rr = i / 14, g = i % 14;
        int y  = rr + 3;            // [3,53)
        int x0 = 4 * g;             // {0,...,52}
        float4 lu, cu, lv, cv;
        lap4(&Au[0][0], y, x0 + 4, ASTR, lu, cu);
        lap4(&Av[0][0], y, x0 + 4, ASTR, lv, cv);
        float4 y1u, y1v, kuq, kvq;
        #pragma unroll
        for (int j = 0; j < 4; ++j) {
            float u = el(cu, j), v = el(cv, j);
            float uv2 = u * v * v;
            float ku = fmaf(mu_u, el(lu, j), fmaf(NA, uv2, ff * (1.0f - u)));
            float kv = fmaf(mu_v, el(lv, j), fmaf(NB, uv2, -kpf * v));
            elr(y1u, j) = fmaf(0.25f, ku, u);
            elr(y1v, j) = fmaf(0.25f, kv, v);
            elr(kuq, j) = ku; elr(kvq, j) = kv;
        }
        if (x0 >= 4 && x0 <= 48) {
            *(float4*)&Bu[y - 3][x0] = y1u;
            *(float4*)&Bv[y - 3][x0] = y1v;
        } else {
            #pragma unroll
            for (int j = 0; j < 4; ++j) {
                int x = x0 + j;
                if (x >= 3 && x < 53) { Bu[y-3][x] = el(y1u,j); Bv[y-3][x] = el(y1v,j); }
            }
        }
        if (y >= 12 && y < 44 && x0 >= 12 && x0 <= 40) {
            *(float4*)&ACu[y - 12][x0 - 12] = kuq;
            *(float4*)&ACv[y - 12][x0 - 12] = kvq;
        }
    }
    __syncthreads();

    // ---- stage 2: k2 over [6,50)^2 ; Y2 = u0 + 0.25 k2 -> C ----
    for (int i = tid; i < 44 * 12; i += 256) {
        int rr = i / 12, g = i % 12;
        int y  = rr + 6;            // [6,50)
        int x0 = 4 + 4 * g;         // {4,...,48}
        float4 lu, cu, lv, cv;
        lap4(&Bu[0][0], y - 3, x0, BSTR, lu, cu);
        lap4(&Bv[0][0], y - 3, x0, BSTR, lv, cv);
        float4 au = *(const float4*)&Au[y][x0 + 4];
        float4 av = *(const float4*)&Av[y][x0 + 4];
        float4 y2u, y2v, kuq, kvq;
        #pragma unroll
        for (int j = 0; j < 4; ++j) {
            float u = el(cu, j), v = el(cv, j);
            float uv2 = u * v * v;
            float ku = fmaf(mu_u, el(lu, j), fmaf(NA, uv2, ff * (1.0f - u)));
            float kv = fmaf(mu_v, el(lv, j), fmaf(NB, uv2, -kpf * v));
            elr(y2u, j) = fmaf(0.25f, ku, el(au, j));
            elr(y2v, j) = fmaf(0.25f, kv, el(av, j));
            elr(kuq, j) = ku; elr(kvq, j) = kv;
        }
        if (x0 >= 8 && x0 <= 44) {
            *(float4*)&Cu[y - 6][x0] = y2u;
            *(float4*)&Cv[y - 6][x0] = y2v;
        } else {
            #pragma unroll
            for (int j = 0; j < 4; ++j) {
                int x = x0 + j;
                if (x >= 6 && x < 50) { Cu[y-6][x] = el(y2u,j); Cv[y-6][x] = el(y2v,j); }
            }
        }
        if (y >= 12 && y < 44 && x0 >= 12 && x0 <= 40) {
            float4 tu = *(const float4*)&ACu[y - 12][x0 - 12];
            float4 tv = *(const float4*)&ACv[y - 12][x0 - 12];
            *(float4*)&ACu[y - 12][x0 - 12] = f4_fma(2.0f, kuq, tu);
            *(float4*)&ACv[y - 12][x0 - 12] = f4_fma(2.0f, kvq, tv);
        }
    }
    __syncthreads();

    // ---- stage 3: k3 over [9,47)^2 ; Y3 = u0 + 0.5 k3 -> B (reuse) ----
    for (int i = tid; i < 38 * 10; i += 256) {
        int rr = i / 10, g = i % 10;
        int y  = rr + 9;            // [9,47)
        int x0 = 8 + 4 * g;         // {8,...,44}
        float4 lu, cu, lv, cv;
        lap4(&Cu[0][0], y - 6, x0, CSTR, lu, cu);
        lap4(&Cv[0][0], y - 6, x0, CSTR, lv, cv);
        float4 au = *(const float4*)&Au[y][x0 + 4];
        float4 av = *(const float4*)&Av[y][x0 + 4];
        float4 y3u, y3v, kuq, kvq;
        #pragma unroll
        for (int j = 0; j < 4; ++j) {
            float u = el(cu, j), v = el(cv, j);
            float uv2 = u * v * v;
            float ku = fmaf(mu_u, el(lu, j), fmaf(NA, uv2, ff * (1.0f - u)));
            float kv = fmaf(mu_v, el(lv, j), fmaf(NB, uv2, -kpf * v));
            elr(y3u, j) = fmaf(0.5f, ku, el(au, j));
            elr(y3v, j) = fmaf(0.5f, kv, el(av, j));
            elr(kuq, j) = ku; elr(kvq, j) = kv;
        }
        if (x0 >= 12 && x0 <= 40) {
            *(float4*)&Bu[y - 3][x0] = y3u;
            *(float4*)&Bv[y - 3][x0] = y3v;
        } else {
            #pragma unroll
            for (int j = 0; j < 4; ++j) {
                int x = x0 + j;
                if (x >= 9 && x < 47) { Bu[y-3][x] = el(y3u,j); Bv[y-3][x] = el(y3v,j); }
            }
        }
        if (y >= 12 && y < 44 && x0 >= 12 && x0 <= 40) {
            float4 tu = *(const float4*)&ACu[y - 12][x0 - 12];
            float4 tv = *(const float4*)&ACv[y - 12][x0 - 12];
            *(float4*)&ACu[y - 12][x0 - 12] = f4_fma(2.0f, kuq, tu);
            *(float4*)&ACv[y - 12][x0 - 12] = f4_fma(2.0f, kvq, tv);
        }
    }
    __syncthreads();

    // ---- stage 4: k4 over [12,44)^2 ; write output ----
    for (int i = tid; i < 32 * 8; i += 256) {
        int rr = i / 8, g = i % 8;
        int y  = rr + 12;           // [12,44)
        int x0 = 12 + 4 * g;        // {12,...,40}
        float4 lu, cu, lv, cv;
        lap4(&Bu[0][0], y - 3, x0, BSTR, lu, cu);
        lap4(&Bv[0][0], y - 3, x0, BSTR, lv, cv);
        float4 au = *(const float4*)&Au[y][x0 + 4];
        float4 av = *(const float4*)&Av[y][x0 + 4];
        float4 acu = *(const float4*)&ACu[y - 12][x0 - 12];
        float4 acv = *(const float4*)&ACv[y - 12][x0 - 12];
        float4 ou, ov;
        #pragma unroll
        for (int j = 0; j < 4; ++j) {
            float u = el(cu, j), v = el(cv, j);
            float uv2 = u * v * v;
            float ku = fmaf(mu_u, el(lu, j), fmaf(NA, uv2, ff * (1.0f - u)));
            float kv = fmaf(mu_v, el(lv, j), fmaf(NB, uv2, -kpf * v));
            elr(ou, j) = fmaf(0.5f / 6.0f, el(acu, j) + ku, el(au, j));
            elr(ov, j) = fmaf(0.5f / 6.0f, el(acv, j) + kv, el(av, j));
        }
        int gy = blockIdx.y * TS + (y - 12);
        int gx = blockIdx.x * TS + (x0 - 12);
        size_t off = (size_t)gy * 1024 + gx;
        *(float4*)(out + baseU + off) = ou;
        *(float4*)(out + baseV + off) = ov;
    }
}

extern "C" void kernel_launch(void* const* d_in, const int* in_sizes, int n_in,
                              void* d_out, int out_size, void* d_ws, size_t ws_size,
                              hipStream_t stream) {
    const float* h   = (const float*)d_in[0];
    const float* pCA = (const float*)d_in[1];
    const float* pCB = (const float*)d_in[2];
    const float* pNA = (const float*)d_in[3];
    const float* pNB = (const float*)d_in[4];
    const float* pf  = (const float*)d_in[5];
    const float* pk  = (const float*)d_in[6];
    float* out = (float*)d_out;

    dim3 grid(1024 / TS, 1024 / TS, 16);
    dim3 block(256);
    rcnn_rk4_fused<<<grid, block, 0, stream>>>(h, pCA, pCB, pNA, pNB, pf, pk, out);
}